// Round 1
// baseline (705.638 us; speedup 1.0000x reference)
//
#include <hip/hip_runtime.h>

typedef unsigned short u16;
typedef __attribute__((ext_vector_type(8))) short short8;
typedef __attribute__((ext_vector_type(4))) float f32x4;

__device__ __forceinline__ float bf2f(u16 u){ return __uint_as_float(((unsigned)u)<<16); }
__device__ __forceinline__ u16 f2bf(float f){
  unsigned u = __float_as_uint(f);
  unsigned r = u + 0x7fffu + ((u>>16)&1u);   // RNE (no NaN/inf in this problem)
  return (u16)(r>>16);
}

#define MFMA16(a,b,c) __builtin_amdgcn_mfma_f32_16x16x32_bf16(a,b,c,0,0,0)

// ---- attn LDS layout (u16 offsets). Strides 264/72: row-stride ≡ 4 banks →
// fragment reads serialize only to the wave64 minimum (no net conflict).
static constexpr int XS_STR  = 264;
static constexpr int PS_STR  = 72;
static constexpr int WT_STR  = 72;
static constexpr int XHI_OFF = 0;         // 64x264
static constexpr int XLO_OFF = 16896;
static constexpr int GHI_OFF = 33792;     // 64x264 G-hi
static constexpr int GLO_OFF = 50688;     // 64x264 G-lo
static constexpr int XVT_OFF = 33792;     // transient 256x72 Xv^T, aliases Ghi+Glo
static constexpr int PS_OFF  = 67584;     // 64x72
static constexpr int SMF_OFF = 72192;     // 64 rows x 4 zq x (mx,sum) f32
static constexpr int SMEM_BYTES = (72192 + 1024)*2;   // 146432 B -> 1 block/CU, 16 waves

// ---- mh LDS
static constexpr int MH_SMEM = 70656*2;   // Qhi/Qlo 64x264 + Chi/Clo 256x72

// ---- ws layout (u16): mhi[524288] | mlo[524288] | khi[65536] | klo[65536]
//                       | vT[65536] | soP[4096 u16 = 2048 f32]   (~2.38 MB)

// prep: 0..63 ksplit | 64..79 vT | 80..335 so | 336..847 zero out
__global__ void prep_kernel(const float* __restrict__ k, const float* __restrict__ v,
                            const float* __restrict__ o, u16* __restrict__ khi,
                            u16* __restrict__ klo, u16* __restrict__ vT,
                            float* __restrict__ soP, float4* __restrict__ outz){
  __shared__ float Ts[64*65];
  const int blk = blockIdx.x, tid = threadIdx.x;
  if (blk < 64){
    int base = blk*1024 + tid*4;
    const float4 f4 = *(const float4*)(k + base);
    ushort4 hv, lv;
    hv.x=f2bf(f4.x); lv.x=f2bf(f4.x-bf2f(hv.x));
    hv.y=f2bf(f4.y); lv.y=f2bf(f4.y-bf2f(hv.y));
    hv.z=f2bf(f4.z); lv.z=f2bf(f4.z-bf2f(hv.z));
    hv.w=f2bf(f4.w); lv.w=f2bf(f4.w-bf2f(hv.w));
    *(ushort4*)&khi[base] = hv;
    *(ushort4*)&klo[base] = lv;
  } else if (blk < 80){
    int t = blk - 64;
    const int bi = (t>>2)<<6, bj = (t&3)<<6;
    #pragma unroll
    for (int p=0;p<4;p++){
      int idx4 = tid + (p<<8);
      int i = idx4 >> 4, c4 = (idx4 & 15) << 2;
      const float4 f4 = *(const float4*)(v + ((bi+i)<<8) + bj + c4);
      Ts[i*65+c4]=f4.x; Ts[i*65+c4+1]=f4.y; Ts[i*65+c4+2]=f4.z; Ts[i*65+c4+3]=f4.w;
    }
    __syncthreads();
    #pragma unroll
    for (int p=0;p<2;p++){
      int ch = tid + (p<<8);
      int j = ch >> 3, i8 = (ch & 7) << 3;
      short8 t8;
      #pragma unroll
      for (int e=0;e<8;e++) t8[e] = (short)f2bf(Ts[(i8+e)*65 + j]);
      *(short8*)&vT[((bj+j)<<8) + bi + i8] = t8;
    }
  } else if (blk < 336){
    int p = blk - 80;                      // 256 blocks: 8 h x 32 chunks of 8 rows
    int h = p >> 5, base = (p & 31) << 3;
    int w = tid >> 6, l = tid & 63;
    #pragma unroll
    for (int i=0;i<2;i++){
      int row = base + w*2 + i;
      const float4 f4 = *(const float4*)(o + (((h<<8)+row)<<8) + (l<<2));
      float s = f4.x + f4.y + f4.z + f4.w;
      #pragma unroll
      for (int off=32; off>=1; off>>=1) s += __shfl_xor(s, off, 64);
      if (l==0) soP[(h<<8)+row] = s;
    }
  } else {
    int z = blk - 336;                     // 512 blocks x 4096 float4
    const float4 zf4 = {0.f,0.f,0.f,0.f};
    #pragma unroll
    for (int i=0;i<16;i++) outz[z*4096 + i*256 + tid] = zf4;
  }
}

// MhT[h][dp][d] = sum_ko q[h][d][ko]*k[dp][ko], hi/lo bf16 via 3-term MFMA
__global__ __launch_bounds__(256,1) void mh_kernel(
    const float* __restrict__ q, const u16* __restrict__ khi,
    const u16* __restrict__ klo, u16* __restrict__ mhi, u16* __restrict__ mlo)
{
  extern __shared__ u16 sm[];
  u16* Qhi = sm;
  u16* Qlo = sm + 16896;
  u16* Chi = sm + 33792;
  u16* Clo = sm + 52224;

  const int tid = threadIdx.x;
  const int w = tid >> 6, lane = tid & 63;
  const int quad = lane >> 4, m16 = lane & 15;
  const int cw = w << 6, koq = quad << 3;
  const int h = blockIdx.x >> 2, dt = (blockIdx.x & 3) << 6;

  #pragma unroll
  for (int i=0;i<16;i++){
    int idx4 = i*256 + tid;
    int tr = idx4 >> 6, c4 = (idx4 & 63) << 2;
    const float4 xv = *(const float4*)(q + (((h<<8)+dt+tr)<<8) + c4);
    ushort4 hv, lv;
    hv.x=f2bf(xv.x); lv.x=f2bf(xv.x-bf2f(hv.x));
    hv.y=f2bf(xv.y); lv.y=f2bf(xv.y-bf2f(hv.y));
    hv.z=f2bf(xv.z); lv.z=f2bf(xv.z-bf2f(hv.z));
    hv.w=f2bf(xv.w); lv.w=f2bf(xv.w-bf2f(hv.w));
    *(ushort4*)&Qhi[tr*XS_STR + c4] = hv;
    *(ushort4*)&Qlo[tr*XS_STR + c4] = lv;
  }
  __syncthreads();

  const f32x4 zf = {0.f,0.f,0.f,0.f};
  f32x4 acc[4][4];
  #pragma unroll
  for (int r=0;r<4;r++)
    #pragma unroll
    for (int c=0;c<4;c++) acc[r][c] = zf;

  short8 Bh[2][4], Bl[2][4];
  #pragma unroll
  for (int c=0;c<4;c++){
    Bh[0][c] = *(const short8*)&khi[(cw + c*16 + m16)*256 + koq];
    Bl[0][c] = *(const short8*)&klo[(cw + c*16 + m16)*256 + koq];
  }
  #pragma unroll
  for (int kk=0;kk<8;kk++){
    const int cur = kk&1, nxt = cur^1;
    if (kk<7){
      const int ko2 = ((kk+1)<<5) + koq;
      #pragma unroll
      for (int c=0;c<4;c++){
        Bh[nxt][c] = *(const short8*)&khi[(cw + c*16 + m16)*256 + ko2];
        Bl[nxt][c] = *(const short8*)&klo[(cw + c*16 + m16)*256 + ko2];
      }
    }
    const int ko = (kk<<5) + koq;
    short8 Ah[4], Al[4];
    #pragma unroll
    for (int r=0;r<4;r++) Ah[r] = *(const short8*)&Qhi[(r*16+m16)*XS_STR + ko];
    #pragma unroll
    for (int r=0;r<4;r++) Al[r] = *(const short8*)&Qlo[(r*16+m16)*XS_STR + ko];
    #pragma unroll
    for (int r=0;r<4;r++)
      #pragma unroll
      for (int c=0;c<4;c++){
        acc[r][c] = MFMA16(Ah[r], Bh[cur][c], acc[r][c]);
        acc[r][c] = MFMA16(Ah[r], Bl[cur][c], acc[r][c]);
        acc[r][c] = MFMA16(Al[r], Bh[cur][c], acc[r][c]);
      }
  }

  #pragma unroll
  for (int r=0;r<4;r++)
    #pragma unroll
    for (int c=0;c<4;c++)
      #pragma unroll
      for (int g=0; g<4; g++){
        int drow = r*16 + quad*4 + g;
        int dp   = cw + c*16 + m16;
        float vv = acc[r][c][g];
        u16 hh = f2bf(vv);
        Chi[dp*WT_STR + drow] = hh;
        Clo[dp*WT_STR + drow] = f2bf(vv - bf2f(hh));
      }
  __syncthreads();

  #pragma unroll
  for (int p=0;p<8;p++){
    int ch = tid + (p<<8);
    int dp = ch >> 3, i8 = (ch & 7) << 3;
    *(int4*)&mhi[(((h<<8)+dp)<<8) + dt + i8] = *(const int4*)&Chi[dp*WT_STR + i8];
    *(int4*)&mlo[(((h<<8)+dp)<<8) + dt + i8] = *(const int4*)&Clo[dp*WT_STR + i8];
  }
}

// Merged attention: blocks [0,512) branch 0 (per-(b,y), heads 0..3),
// [512,1024) branch 1 (per-(b,x), heads 4..7). out pre-zeroed; atomicAdd.
// 16 waves (1024 thr) for 2x occupancy: mm3/Xv/Y split 2rt x 8ct (2x global-B
// redundancy, L2-resident); logits split 16-row x 16-z with B-side Xhi in regs
// (XB, 32 VGPR). Ghi+Glo written together (dual buffer) -> 3 barriers/head.
// Y B-side Xv^T fragments hoisted to regs once; Xv^T LDS aliases Ghi/Glo.
__global__ __launch_bounds__(1024,4) void attn_kernel(
    const float* __restrict__ x, const u16* __restrict__ mhiP,
    const u16* __restrict__ mloP, const u16* __restrict__ vT,
    const float* __restrict__ soP, float* __restrict__ out)
{
  extern __shared__ u16 sm[];
  u16* Xhi = sm + XHI_OFF;
  u16* Xlo = sm + XLO_OFF;
  u16* Ghi = sm + GHI_OFF;
  u16* Glo = sm + GLO_OFF;
  u16* Xvt = sm + XVT_OFF;
  float* SMf = (float*)(sm + SMF_OFF);   // [row][zq][mx,sum]
  u16* Ps  = sm + PS_OFF;

  const int tid  = threadIdx.x;
  const int w    = tid >> 6, lane = tid & 63;
  const int quad = lane >> 4, m16 = lane & 15;
  const int br   = blockIdx.x >> 9;
  const int idx  = blockIdx.x & 511;
  const int b    = idx >> 6, s = idx & 63;
  const int rb   = (w >> 3) << 5;     // mm3/Xv/Y: 32-row tile
  const int cb   = (w & 7) << 5;      // mm3/Xv/Y: 32-col strip
  const int rs   = (w >> 2) << 4;     // logits: 16-row strip
  const int zq   = w & 3;             // logits: 16-z strip
  const int koq  = quad << 3;

  auto tok = [&](int t)->int {
    int m = br ? s : t;
    int n = br ? t : s;
    return (((b<<6) + m) << 14) + (n << 8);
  };

  // ---- stage X hi/lo (4096 float4, 4 iters x 1024 threads)
  #pragma unroll
  for (int i=0;i<4;i++){
    int idx4 = i*1024 + tid;
    int tr = idx4 >> 6, c4 = (idx4 & 63) << 2;
    const float4 xv = *(const float4*)(x + tok(tr) + c4);
    ushort4 hv, lv;
    hv.x=f2bf(xv.x); lv.x=f2bf(xv.x-bf2f(hv.x));
    hv.y=f2bf(xv.y); lv.y=f2bf(xv.y-bf2f(hv.y));
    hv.z=f2bf(xv.z); lv.z=f2bf(xv.z-bf2f(hv.z));
    hv.w=f2bf(xv.w); lv.w=f2bf(xv.w-bf2f(hv.w));
    *(ushort4*)&Xhi[tr*XS_STR + c4] = hv;
    *(ushort4*)&Xlo[tr*XS_STR + c4] = lv;
  }
  __syncthreads();

  // ---- persist logits B-side Xhi fragments (own 16-z strip): 32 VGPRs
  short8 XB[8];
  #pragma unroll
  for (int kk=0;kk<8;kk++)
    XB[kk] = *(const short8*)&Xhi[((zq<<4) + m16)*XS_STR + (kk<<5) + koq];

  const f32x4 zf = {0.f,0.f,0.f,0.f};
  f32x4 acc[2][2];

  // ---- Xv = Xhi @ vT (32x32 wave tile); store Xv^T (unscaled) in LDS
  {
    #pragma unroll
    for (int r=0;r<2;r++){ acc[r][0] = zf; acc[r][1] = zf; }
    #pragma unroll
    for (int kk=0;kk<8;kk++){
      const int ko = (kk<<5) + koq;
      short8 A[2], Bf[2];
      #pragma unroll
      for (int r=0;r<2;r++) A[r]  = *(const short8*)&Xhi[(rb + r*16 + m16)*XS_STR + ko];
      #pragma unroll
      for (int c=0;c<2;c++) Bf[c] = *(const short8*)&vT[(cb + c*16 + m16)*256 + ko];
      #pragma unroll
      for (int r=0;r<2;r++)
        #pragma unroll
        for (int c=0;c<2;c++) acc[r][c] = MFMA16(A[r], Bf[c], acc[r][c]);
    }
    #pragma unroll
    for (int r=0;r<2;r++)
      #pragma unroll
      for (int c=0;c<2;c++)
        #pragma unroll
        for (int g=0; g<4; g++){
          int z  = rb + r*16 + quad*4 + g;
          int vc = cb + c*16 + m16;
          Xvt[vc*WT_STR + z] = f2bf(acc[r][c][g]);
        }
  }
  __syncthreads();                       // Xvt visible

  // ---- hoist Y B-side fragments to regs (16 VGPR, constant over heads)
  short8 XvB[2][2];
  #pragma unroll
  for (int kk=0;kk<2;kk++)
    #pragma unroll
    for (int c=0;c<2;c++)
      XvB[kk][c] = *(const short8*)&Xvt[(cb + c*16 + m16)*WT_STR + (kk<<5) + koq];
  __syncthreads();                       // Xvt reads done -> Ghi/Glo may overwrite

  f32x4 Z[2][2];
  #pragma unroll
  for (int r=0;r<2;r++){ Z[r][0] = zf; Z[r][1] = zf; }

  for (int h=0; h<4; h++){
    const int gh = br*4 + h;
    const u16* __restrict__ Whi = mhiP + gh*65536;
    const u16* __restrict__ Wlo = mloP + gh*65536;

    // ---- G = X @ Mh[gh] (3-term hi/lo), 32x32 wave tile; write Ghi AND Glo
    #pragma unroll
    for (int r=0;r<2;r++){ acc[r][0] = zf; acc[r][1] = zf; }
    #pragma unroll
    for (int kk=0;kk<8;kk++){
      const int ko = (kk<<5) + koq;
      short8 Ah[2], Al[2], Bh[2], Bl[2];
      #pragma unroll
      for (int r=0;r<2;r++){
        Ah[r] = *(const short8*)&Xhi[(rb + r*16 + m16)*XS_STR + ko];
        Al[r] = *(const short8*)&Xlo[(rb + r*16 + m16)*XS_STR + ko];
      }
      #pragma unroll
      for (int c=0;c<2;c++){
        Bh[c] = *(const short8*)&Whi[(cb + c*16 + m16)*256 + ko];
        Bl[c] = *(const short8*)&Wlo[(cb + c*16 + m16)*256 + ko];
      }
      #pragma unroll
      for (int r=0;r<2;r++)
        #pragma unroll
        for (int c=0;c<2;c++){
          acc[r][c] = MFMA16(Ah[r], Bh[c], acc[r][c]);
          acc[r][c] = MFMA16(Ah[r], Bl[c], acc[r][c]);
          acc[r][c] = MFMA16(Al[r], Bh[c], acc[r][c]);
        }
    }
    #pragma unroll
    for (int r=0;r<2;r++)
      #pragma unroll
      for (int c=0;c<2;c++)
        #pragma unroll
        for (int g=0; g<4; g++){
          int row = rb + r*16 + quad*4 + g;
          int col = cb + c*16 + m16;
          float vv = acc[r][c][g];
          u16 hh = f2bf(vv);
          Ghi[row*XS_STR + col] = hh;
          Glo[row*XS_STR + col] = f2bf(vv - bf2f(hh));
        }
    __syncthreads();                     // bar1: Ghi+Glo visible

    // ---- logits (16 rows x 16 z): Ghi@Xhi(regs) + Ghi@Xlo + Glo@Xhi(regs)
    f32x4 L = zf;
    #pragma unroll
    for (int kk=0;kk<8;kk++){
      const int ko = (kk<<5) + koq;
      short8 Ahi = *(const short8*)&Ghi[(rs + m16)*XS_STR + ko];
      short8 Alo = *(const short8*)&Glo[(rs + m16)*XS_STR + ko];
      short8 Bxl = *(const short8*)&Xlo[((zq<<4) + m16)*XS_STR + ko];
      L = MFMA16(Ahi, XB[kk], L);
      L = MFMA16(Ahi, Bxl, L);
      L = MFMA16(Alo, XB[kk], L);
    }

    // ---- softmax: local (16-z strip) max/sum; merge 4 strips via SMf
    float mxl[4], sml[4];
    #pragma unroll
    for (int g=0; g<4; g++){
      float mx = L[g];
      #pragma unroll
      for (int off=1; off<16; off<<=1) mx = fmaxf(mx, __shfl_xor(mx, off, 64));
      float e = __expf(L[g]-mx); L[g] = e;
      float sum = e;
      #pragma unroll
      for (int off=1; off<16; off<<=1) sum += __shfl_xor(sum, off, 64);
      mxl[g] = mx; sml[g] = sum;
      if (m16 == 0){
        int row = rs + quad*4 + g;
        SMf[row*8 + zq*2]     = mx;
        SMf[row*8 + zq*2 + 1] = sum;
      }
    }
    __syncthreads();                     // bar2: SMf visible
    #pragma unroll
    for (int g=0; g<4; g++){
      int row = rs + quad*4 + g;
      float m0=SMf[row*8+0], s0=SMf[row*8+1];
      float m1=SMf[row*8+2], s1=SMf[row*8+3];
      float m2=SMf[row*8+4], s2=SMf[row*8+5];
      float m3=SMf[row*8+6], s3=SMf[row*8+7];
      float M  = fmaxf(fmaxf(m0,m1), fmaxf(m2,m3));
      float denom = s0*__expf(m0-M) + s1*__expf(m1-M)
                  + s2*__expf(m2-M) + s3*__expf(m3-M);
      float scale = __expf(mxl[g]-M)/denom;
      Ps[row*PS_STR + (zq<<4) + m16] = f2bf(L[g]*scale);
    }
    __syncthreads();                     // bar3: Ps visible

    // ---- Y = P @ Xv (32x32 wave tile, B from regs); Z += so * Y
    #pragma unroll
    for (int r=0;r<2;r++){ acc[r][0] = zf; acc[r][1] = zf; }
    #pragma unroll
    for (int kk=0;kk<2;kk++){
      const int ko = (kk<<5) + koq;
      short8 Ap[2];
      #pragma unroll
      for (int r=0;r<2;r++) Ap[r] = *(const short8*)&Ps[(rb + r*16 + m16)*PS_STR + ko];
      #pragma unroll
      for (int r=0;r<2;r++)
        #pragma unroll
        for (int c=0;c<2;c++) acc[r][c] = MFMA16(Ap[r], XvB[kk][c], acc[r][c]);
    }
    float sc[2];
    sc[0] = soP[gh*256 + cb + m16];
    sc[1] = soP[gh*256 + cb + 16 + m16];
    #pragma unroll
    for (int r=0;r<2;r++)
      #pragma unroll
      for (int c=0;c<2;c++)
        #pragma unroll
        for (int g=0; g<4; g++) Z[r][c][g] += sc[c]*acc[r][c][g];
    // loop boundary safe with 3 barriers/head: next head's G writes follow this
    // head's bar3 (all G/SMf/Ps reads for head h are barrier-ordered before any
    // head h+1 writes to the same region).
  }

  // ---- epilogue: atomic accumulate into pre-zeroed out
  #pragma unroll
  for (int r=0;r<2;r++)
    #pragma unroll
    for (int c=0;c<2;c++)
      #pragma unroll
      for (int g=0; g<4; g++){
        int t   = rb + r*16 + quad*4 + g;
        int col = cb + c*16 + m16;
        atomicAdd(&out[tok(t) + col], Z[r][c][g]);
      }
}

extern "C" void kernel_launch(void* const* d_in, const int* in_sizes, int n_in,
                              void* d_out, int out_size, void* d_ws, size_t ws_size,
                              hipStream_t stream) {
  const float* x = (const float*)d_in[0];
  const float* q = (const float*)d_in[1];
  const float* k = (const float*)d_in[2];
  const float* v = (const float*)d_in[3];
  const float* o = (const float*)d_in[4];
  u16* ws   = (u16*)d_ws;                    // ~2.38 MB
  u16* mhi  = ws;
  u16* mlo  = ws + 524288;
  u16* khi  = ws + 1048576;
  u16* klo  = ws + 1114112;
  u16* vT   = ws + 1179648;
  float* soP = (float*)(ws + 1245184);
  float* out = (float*)d_out;

  prep_kernel<<<848, 256, 0, stream>>>(k, v, o, khi, klo, vT, soP, (float4*)d_out);
  (void)hipFuncSetAttribute(reinterpret_cast<const void*>(&mh_kernel),
                            hipFuncAttributeMaxDynamicSharedMemorySize, MH_SMEM);
  mh_kernel<<<32, 256, MH_SMEM, stream>>>(q, khi, klo, mhi, mlo);

  (void)hipFuncSetAttribute(reinterpret_cast<const void*>(&attn_kernel),
                            hipFuncAttributeMaxDynamicSharedMemorySize, SMEM_BYTES);
  attn_kernel<<<1024, 1024, SMEM_BYTES, stream>>>(x, mhi, mlo, vT, soP, out);
}

// Round 2
// 613.434 us; speedup vs baseline: 1.1503x; 1.1503x over previous
//
#include <hip/hip_runtime.h>

typedef unsigned short u16;
typedef __attribute__((ext_vector_type(8))) short short8;
typedef __attribute__((ext_vector_type(4))) float f32x4;

__device__ __forceinline__ float bf2f(u16 u){ return __uint_as_float(((unsigned)u)<<16); }
__device__ __forceinline__ u16 f2bf(float f){
  unsigned u = __float_as_uint(f);
  unsigned r = u + 0x7fffu + ((u>>16)&1u);   // RNE (no NaN/inf in this problem)
  return (u16)(r>>16);
}

#define MFMA16(a,b,c) __builtin_amdgcn_mfma_f32_16x16x32_bf16(a,b,c,0,0,0)

// ---- attn LDS layout (u16 offsets). Strides 264/72: row-stride ≡ 4 banks →
// fragment reads serialize only to the wave64 minimum (no net conflict).
static constexpr int XS_STR  = 264;
static constexpr int PS_STR  = 72;
static constexpr int WT_STR  = 72;
static constexpr int XHI_OFF = 0;         // 64x264
static constexpr int XLO_OFF = 16896;
static constexpr int GHI_OFF = 33792;     // 64x264 G-hi
static constexpr int GLO_OFF = 50688;     // 64x264 G-lo
static constexpr int XVT_OFF = 33792;     // transient 256x72 Xv^T, aliases Ghi/Glo
static constexpr int PS_OFF  = 67584;     // 64x72
static constexpr int SMF_OFF = 72192;     // 64 rows x 2 halves x (mx,sum) f32
static constexpr int SMEM_BYTES = (72192 + 512)*2;   // 145408 B -> 1 block/CU, 8 waves

// ---- mh LDS
static constexpr int MH_SMEM = 70656*2;   // Qhi/Qlo 64x264 + Chi/Clo 256x72

// ---- ws layout (u16): mhi[524288] | mlo[524288] | khi[65536] | klo[65536]
//                       | vT[65536] | soP[4096 u16 = 2048 f32]   (~2.38 MB)

// prep: 0..63 ksplit | 64..79 vT | 80..335 so | 336..847 zero out
__global__ void prep_kernel(const float* __restrict__ k, const float* __restrict__ v,
                            const float* __restrict__ o, u16* __restrict__ khi,
                            u16* __restrict__ klo, u16* __restrict__ vT,
                            float* __restrict__ soP, float4* __restrict__ outz){
  __shared__ float Ts[64*65];
  const int blk = blockIdx.x, tid = threadIdx.x;
  if (blk < 64){
    int base = blk*1024 + tid*4;
    const float4 f4 = *(const float4*)(k + base);
    ushort4 hv, lv;
    hv.x=f2bf(f4.x); lv.x=f2bf(f4.x-bf2f(hv.x));
    hv.y=f2bf(f4.y); lv.y=f2bf(f4.y-bf2f(hv.y));
    hv.z=f2bf(f4.z); lv.z=f2bf(f4.z-bf2f(hv.z));
    hv.w=f2bf(f4.w); lv.w=f2bf(f4.w-bf2f(hv.w));
    *(ushort4*)&khi[base] = hv;
    *(ushort4*)&klo[base] = lv;
  } else if (blk < 80){
    int t = blk - 64;
    const int bi = (t>>2)<<6, bj = (t&3)<<6;
    #pragma unroll
    for (int p=0;p<4;p++){
      int idx4 = tid + (p<<8);
      int i = idx4 >> 4, c4 = (idx4 & 15) << 2;
      const float4 f4 = *(const float4*)(v + ((bi+i)<<8) + bj + c4);
      Ts[i*65+c4]=f4.x; Ts[i*65+c4+1]=f4.y; Ts[i*65+c4+2]=f4.z; Ts[i*65+c4+3]=f4.w;
    }
    __syncthreads();
    #pragma unroll
    for (int p=0;p<2;p++){
      int ch = tid + (p<<8);
      int j = ch >> 3, i8 = (ch & 7) << 3;
      short8 t8;
      #pragma unroll
      for (int e=0;e<8;e++) t8[e] = (short)f2bf(Ts[(i8+e)*65 + j]);
      *(short8*)&vT[((bj+j)<<8) + bi + i8] = t8;
    }
  } else if (blk < 336){
    int p = blk - 80;                      // 256 blocks: 8 h x 32 chunks of 8 rows
    int h = p >> 5, base = (p & 31) << 3;
    int w = tid >> 6, l = tid & 63;
    #pragma unroll
    for (int i=0;i<2;i++){
      int row = base + w*2 + i;
      const float4 f4 = *(const float4*)(o + (((h<<8)+row)<<8) + (l<<2));
      float s = f4.x + f4.y + f4.z + f4.w;
      #pragma unroll
      for (int off=32; off>=1; off>>=1) s += __shfl_xor(s, off, 64);
      if (l==0) soP[(h<<8)+row] = s;
    }
  } else {
    int z = blk - 336;                     // 512 blocks x 4096 float4
    const float4 zf4 = {0.f,0.f,0.f,0.f};
    #pragma unroll
    for (int i=0;i<16;i++) outz[z*4096 + i*256 + tid] = zf4;
  }
}

// MhT[h][dp][d] = sum_ko q[h][d][ko]*k[dp][ko], hi/lo bf16 via 3-term MFMA
__global__ __launch_bounds__(256,1) void mh_kernel(
    const float* __restrict__ q, const u16* __restrict__ khi,
    const u16* __restrict__ klo, u16* __restrict__ mhi, u16* __restrict__ mlo)
{
  extern __shared__ u16 sm[];
  u16* Qhi = sm;
  u16* Qlo = sm + 16896;
  u16* Chi = sm + 33792;
  u16* Clo = sm + 52224;

  const int tid = threadIdx.x;
  const int w = tid >> 6, lane = tid & 63;
  const int quad = lane >> 4, m16 = lane & 15;
  const int cw = w << 6, koq = quad << 3;
  const int h = blockIdx.x >> 2, dt = (blockIdx.x & 3) << 6;

  #pragma unroll
  for (int i=0;i<16;i++){
    int idx4 = i*256 + tid;
    int tr = idx4 >> 6, c4 = (idx4 & 63) << 2;
    const float4 xv = *(const float4*)(q + (((h<<8)+dt+tr)<<8) + c4);
    ushort4 hv, lv;
    hv.x=f2bf(xv.x); lv.x=f2bf(xv.x-bf2f(hv.x));
    hv.y=f2bf(xv.y); lv.y=f2bf(xv.y-bf2f(hv.y));
    hv.z=f2bf(xv.z); lv.z=f2bf(xv.z-bf2f(hv.z));
    hv.w=f2bf(xv.w); lv.w=f2bf(xv.w-bf2f(hv.w));
    *(ushort4*)&Qhi[tr*XS_STR + c4] = hv;
    *(ushort4*)&Qlo[tr*XS_STR + c4] = lv;
  }
  __syncthreads();

  const f32x4 zf = {0.f,0.f,0.f,0.f};
  f32x4 acc[4][4];
  #pragma unroll
  for (int r=0;r<4;r++)
    #pragma unroll
    for (int c=0;c<4;c++) acc[r][c] = zf;

  short8 Bh[2][4], Bl[2][4];
  #pragma unroll
  for (int c=0;c<4;c++){
    Bh[0][c] = *(const short8*)&khi[(cw + c*16 + m16)*256 + koq];
    Bl[0][c] = *(const short8*)&klo[(cw + c*16 + m16)*256 + koq];
  }
  #pragma unroll
  for (int kk=0;kk<8;kk++){
    const int cur = kk&1, nxt = cur^1;
    if (kk<7){
      const int ko2 = ((kk+1)<<5) + koq;
      #pragma unroll
      for (int c=0;c<4;c++){
        Bh[nxt][c] = *(const short8*)&khi[(cw + c*16 + m16)*256 + ko2];
        Bl[nxt][c] = *(const short8*)&klo[(cw + c*16 + m16)*256 + ko2];
      }
    }
    const int ko = (kk<<5) + koq;
    short8 Ah[4], Al[4];
    #pragma unroll
    for (int r=0;r<4;r++) Ah[r] = *(const short8*)&Qhi[(r*16+m16)*XS_STR + ko];
    #pragma unroll
    for (int r=0;r<4;r++) Al[r] = *(const short8*)&Qlo[(r*16+m16)*XS_STR + ko];
    #pragma unroll
    for (int r=0;r<4;r++)
      #pragma unroll
      for (int c=0;c<4;c++){
        acc[r][c] = MFMA16(Ah[r], Bh[cur][c], acc[r][c]);
        acc[r][c] = MFMA16(Ah[r], Bl[cur][c], acc[r][c]);
        acc[r][c] = MFMA16(Al[r], Bh[cur][c], acc[r][c]);
      }
  }

  #pragma unroll
  for (int r=0;r<4;r++)
    #pragma unroll
    for (int c=0;c<4;c++)
      #pragma unroll
      for (int g=0; g<4; g++){
        int drow = r*16 + quad*4 + g;
        int dp   = cw + c*16 + m16;
        float vv = acc[r][c][g];
        u16 hh = f2bf(vv);
        Chi[dp*WT_STR + drow] = hh;
        Clo[dp*WT_STR + drow] = f2bf(vv - bf2f(hh));
      }
  __syncthreads();

  #pragma unroll
  for (int p=0;p<8;p++){
    int ch = tid + (p<<8);
    int dp = ch >> 3, i8 = (ch & 7) << 3;
    *(int4*)&mhi[(((h<<8)+dp)<<8) + dt + i8] = *(const int4*)&Chi[dp*WT_STR + i8];
    *(int4*)&mlo[(((h<<8)+dp)<<8) + dt + i8] = *(const int4*)&Clo[dp*WT_STR + i8];
  }
}

// Merged attention: blocks [0,512) branch 0 (per-(b,y), heads 0..3),
// [512,1024) branch 1 (per-(b,x), heads 4..7). out pre-zeroed; atomicAdd.
// 8 waves (512 thr, round-0 tiling): mm3/Xv/Y split 4rt x 2ct (1x global-B,
// dbuf prefetch); logits 16-row x 32-z with B-side Xhi persisted in regs (XB).
// NEW vs round-0: (a) Ghi+Glo written together from mm3 acc -> barriers 5->3
// per head (no Glo readback pass); (b) Y-step B fragments (Xv^T) hoisted to
// 16 VGPRs once, so the Xv^T LDS region is transient and aliases Ghi/Glo,
// paying for the second G buffer. VGPR cap 256 (LDS-capped occupancy) - the
// extra ~32 persistent VGPRs cost nothing. Tripwire: VGPR_Count must be >64
// and WRITE_SIZE ~77MB (else spill).
__global__ __launch_bounds__(512,2) void attn_kernel(
    const float* __restrict__ x, const u16* __restrict__ mhiP,
    const u16* __restrict__ mloP, const u16* __restrict__ vT,
    const float* __restrict__ soP, float* __restrict__ out)
{
  extern __shared__ u16 sm[];
  u16* Xhi = sm + XHI_OFF;
  u16* Xlo = sm + XLO_OFF;
  u16* Ghi = sm + GHI_OFF;
  u16* Glo = sm + GLO_OFF;
  u16* Xvt = sm + XVT_OFF;
  u16* Ps  = sm + PS_OFF;
  float* SMf = (float*)(sm + SMF_OFF);   // [row][half][mx,sum]

  const int tid  = threadIdx.x;
  const int w    = tid >> 6, lane = tid & 63;
  const int quad = lane >> 4, m16 = lane & 15;
  const int br   = blockIdx.x >> 9;
  const int idx  = blockIdx.x & 511;
  const int b    = idx >> 6, s = idx & 63;
  const int cw   = w << 5;            // 32-col strip for mm3/Xv/Y
  const int rs   = (w >> 1) << 4;     // logits: 16-row strip
  const int zh   = w & 1;             // logits: z half (32 cols)
  const int koq  = quad << 3;

  auto tok = [&](int t)->int {
    int m = br ? s : t;
    int n = br ? t : s;
    return (((b<<6) + m) << 14) + (n << 8);
  };

  // ---- stage X hi/lo (4096 float4, 8 iters x 512 threads)
  #pragma unroll
  for (int i=0;i<8;i++){
    int idx4 = i*512 + tid;
    int tr = idx4 >> 6, c4 = (idx4 & 63) << 2;
    const float4 xv = *(const float4*)(x + tok(tr) + c4);
    ushort4 hv, lv;
    hv.x=f2bf(xv.x); lv.x=f2bf(xv.x-bf2f(hv.x));
    hv.y=f2bf(xv.y); lv.y=f2bf(xv.y-bf2f(hv.y));
    hv.z=f2bf(xv.z); lv.z=f2bf(xv.z-bf2f(hv.z));
    hv.w=f2bf(xv.w); lv.w=f2bf(xv.w-bf2f(hv.w));
    *(ushort4*)&Xhi[tr*XS_STR + c4] = hv;
    *(ushort4*)&Xlo[tr*XS_STR + c4] = lv;
  }
  __syncthreads();

  // ---- persist logits B-side Xhi fragments (constant across heads): 64 VGPRs
  short8 XB[16];
  #pragma unroll
  for (int kk=0;kk<8;kk++)
    #pragma unroll
    for (int c=0;c<2;c++)
      XB[kk*2+c] = *(const short8*)&Xhi[((zh<<5) + c*16 + m16)*XS_STR + (kk<<5) + koq];

  const f32x4 zf = {0.f,0.f,0.f,0.f};
  f32x4 acc[4][2];

  // ---- Xv = Xhi @ vT over wave's 32 cols; store Xv^T (unscaled) in LDS
  // (transient: aliases Ghi/Glo; consumed into XvB regs below)
  {
    #pragma unroll
    for (int r=0;r<4;r++){ acc[r][0] = zf; acc[r][1] = zf; }
    #pragma unroll
    for (int kk=0;kk<8;kk++){
      const int ko = (kk<<5) + koq;
      short8 A[4], Bf[2];
      #pragma unroll
      for (int r=0;r<4;r++) A[r]  = *(const short8*)&Xhi[(r*16+m16)*XS_STR + ko];
      #pragma unroll
      for (int c=0;c<2;c++) Bf[c] = *(const short8*)&vT[(cw + c*16 + m16)*256 + ko];
      #pragma unroll
      for (int r=0;r<4;r++)
        #pragma unroll
        for (int c=0;c<2;c++) acc[r][c] = MFMA16(A[r], Bf[c], acc[r][c]);
    }
    #pragma unroll
    for (int r=0;r<4;r++)
      #pragma unroll
      for (int c=0;c<2;c++)
        #pragma unroll
        for (int g=0; g<4; g++){
          int z  = r*16 + quad*4 + g;
          int vc = cw + c*16 + m16;
          Xvt[vc*WT_STR + z] = f2bf(acc[r][c][g]);
        }
  }
  // Each wave reads back only its own cw strip (written by its own lanes) ->
  // no cross-wave visibility needed before the read; one barrier after the
  // reads protects the aliased region from head-0 G writes.
  short8 XvB[2][2];
  #pragma unroll
  for (int kk=0;kk<2;kk++)
    #pragma unroll
    for (int c=0;c<2;c++)
      XvB[kk][c] = *(const short8*)&Xvt[(cw + c*16 + m16)*WT_STR + (kk<<5) + koq];
  __syncthreads();                       // Xvt reads done -> Ghi/Glo may overwrite

  f32x4 Z[4][2];
  #pragma unroll
  for (int r=0;r<4;r++){ Z[r][0] = zf; Z[r][1] = zf; }

  for (int h=0; h<4; h++){
    const int gh = br*4 + h;
    const u16* __restrict__ Whi = mhiP + gh*65536;
    const u16* __restrict__ Wlo = mloP + gh*65536;

    // ---- G = X @ Mh[gh] (3-term hi/lo) over wave's 32-col strip, dbuf B-loads
    #pragma unroll
    for (int r=0;r<4;r++){ acc[r][0] = zf; acc[r][1] = zf; }
    {
      short8 Bh[2][2], Bl[2][2];
      #pragma unroll
      for (int c=0;c<2;c++){
        Bh[0][c] = *(const short8*)&Whi[(cw + c*16 + m16)*256 + koq];
        Bl[0][c] = *(const short8*)&Wlo[(cw + c*16 + m16)*256 + koq];
      }
      #pragma unroll
      for (int kk=0;kk<8;kk++){
        const int cur = kk&1, nxt = cur^1;
        if (kk<7){
          const int ko2 = ((kk+1)<<5) + koq;
          #pragma unroll
          for (int c=0;c<2;c++){
            Bh[nxt][c] = *(const short8*)&Whi[(cw + c*16 + m16)*256 + ko2];
            Bl[nxt][c] = *(const short8*)&Wlo[(cw + c*16 + m16)*256 + ko2];
          }
        }
        const int ko = (kk<<5) + koq;
        short8 Ah[4], Al[4];
        #pragma unroll
        for (int r=0;r<4;r++) Ah[r] = *(const short8*)&Xhi[(r*16+m16)*XS_STR + ko];
        #pragma unroll
        for (int r=0;r<4;r++) Al[r] = *(const short8*)&Xlo[(r*16+m16)*XS_STR + ko];
        #pragma unroll
        for (int r=0;r<4;r++)
          #pragma unroll
          for (int c=0;c<2;c++){
            acc[r][c] = MFMA16(Ah[r], Bh[cur][c], acc[r][c]);
            acc[r][c] = MFMA16(Ah[r], Bl[cur][c], acc[r][c]);
            acc[r][c] = MFMA16(Al[r], Bh[cur][c], acc[r][c]);
          }
      }
    }
    // ---- write Ghi AND Glo together (dual buffer; kills the readback pass)
    #pragma unroll
    for (int r=0;r<4;r++)
      #pragma unroll
      for (int c=0;c<2;c++)
        #pragma unroll
        for (int g=0; g<4; g++){
          int row = r*16 + quad*4 + g;
          int col = cw + c*16 + m16;
          float vv = acc[r][c][g];
          u16 hh = f2bf(vv);
          Ghi[row*XS_STR + col] = hh;
          Glo[row*XS_STR + col] = f2bf(vv - bf2f(hh));
        }
    __syncthreads();                     // bar1: Ghi+Glo visible

    // ---- logits: Ghi@Xhi^T(regs) + Ghi@Xlo^T + Glo@Xhi^T(regs), one pass.
    // Rows rs..rs+16, z half zh.
    f32x4 L[2];
    L[0] = zf; L[1] = zf;
    #pragma unroll
    for (int kk=0;kk<8;kk++){
      const int ko = (kk<<5) + koq;
      short8 Ahi = *(const short8*)&Ghi[(rs+m16)*XS_STR + ko];
      short8 Alo = *(const short8*)&Glo[(rs+m16)*XS_STR + ko];
      #pragma unroll
      for (int c=0;c<2;c++){
        short8 Bxl = *(const short8*)&Xlo[((zh<<5) + c*16 + m16)*XS_STR + ko];
        L[c] = MFMA16(Ahi, XB[kk*2+c], L[c]);
        L[c] = MFMA16(Ahi, Bxl, L[c]);
        L[c] = MFMA16(Alo, XB[kk*2+c], L[c]);
      }
    }

    // ---- softmax: local (32-z half) max/sum, cross-wave merge via SMf
    float mxl[4], sml[4];
    #pragma unroll
    for (int g=0; g<4; g++){
      float mx = fmaxf(L[0][g], L[1][g]);
      #pragma unroll
      for (int off=1; off<16; off<<=1) mx = fmaxf(mx, __shfl_xor(mx, off, 64));
      float sum = 0.f;
      #pragma unroll
      for (int c=0;c<2;c++){ float e = __expf(L[c][g]-mx); L[c][g] = e; sum += e; }
      #pragma unroll
      for (int off=1; off<16; off<<=1) sum += __shfl_xor(sum, off, 64);
      mxl[g] = mx; sml[g] = sum;
      if (m16 == 0){
        int row = rs + quad*4 + g;
        SMf[row*4 + zh*2]     = mx;
        SMf[row*4 + zh*2 + 1] = sum;
      }
    }
    __syncthreads();                     // bar2: SMf visible (G reads also done)
    #pragma unroll
    for (int g=0; g<4; g++){
      int row = rs + quad*4 + g;
      float mxo = SMf[row*4 + (zh^1)*2];
      float smo = SMf[row*4 + (zh^1)*2 + 1];
      float M   = fmaxf(mxl[g], mxo);
      float al  = __expf(mxl[g]-M), ao = __expf(mxo-M);
      float scale = al / (sml[g]*al + smo*ao);
      #pragma unroll
      for (int c=0;c<2;c++)
        Ps[row*PS_STR + (zh<<5) + c*16 + m16] = f2bf(L[c][g]*scale);
    }
    __syncthreads();                     // bar3: Ps visible

    // ---- Y = P @ Xv over wave's 32 cols (B from regs); Z += so * Y
    #pragma unroll
    for (int r=0;r<4;r++){ acc[r][0] = zf; acc[r][1] = zf; }
    #pragma unroll
    for (int kk=0;kk<2;kk++){
      const int ko = (kk<<5) + koq;
      short8 Ap[4];
      #pragma unroll
      for (int r=0;r<4;r++) Ap[r] = *(const short8*)&Ps[(r*16+m16)*PS_STR + ko];
      #pragma unroll
      for (int r=0;r<4;r++)
        #pragma unroll
        for (int c=0;c<2;c++) acc[r][c] = MFMA16(Ap[r], XvB[kk][c], acc[r][c]);
    }
    float sc[2];
    sc[0] = soP[gh*256 + cw + m16];
    sc[1] = soP[gh*256 + cw + 16 + m16];
    #pragma unroll
    for (int r=0;r<4;r++)
      #pragma unroll
      for (int c=0;c<2;c++)
        #pragma unroll
        for (int g=0; g<4; g++) Z[r][c][g] += sc[c]*acc[r][c][g];
    // loop boundary safe with 3 barriers/head: head h+1's G/SMf/Ps writes are
    // barrier-ordered (via bar1/bar2 of h+1) after every wave's reads of the
    // same regions for head h (reads precede bar2(h)/bar3(h) respectively).
  }

  // ---- epilogue: atomic accumulate into pre-zeroed out
  #pragma unroll
  for (int r=0;r<4;r++)
    #pragma unroll
    for (int c=0;c<2;c++)
      #pragma unroll
      for (int g=0; g<4; g++){
        int t   = r*16 + quad*4 + g;
        int col = cw + c*16 + m16;
        atomicAdd(&out[tok(t) + col], Z[r][c][g]);
      }
}

extern "C" void kernel_launch(void* const* d_in, const int* in_sizes, int n_in,
                              void* d_out, int out_size, void* d_ws, size_t ws_size,
                              hipStream_t stream) {
  const float* x = (const float*)d_in[0];
  const float* q = (const float*)d_in[1];
  const float* k = (const float*)d_in[2];
  const float* v = (const float*)d_in[3];
  const float* o = (const float*)d_in[4];
  u16* ws   = (u16*)d_ws;                    // ~2.38 MB
  u16* mhi  = ws;
  u16* mlo  = ws + 524288;
  u16* khi  = ws + 1048576;
  u16* klo  = ws + 1114112;
  u16* vT   = ws + 1179648;
  float* soP = (float*)(ws + 1245184);
  float* out = (float*)d_out;

  prep_kernel<<<848, 256, 0, stream>>>(k, v, o, khi, klo, vT, soP, (float4*)d_out);
  (void)hipFuncSetAttribute(reinterpret_cast<const void*>(&mh_kernel),
                            hipFuncAttributeMaxDynamicSharedMemorySize, MH_SMEM);
  mh_kernel<<<32, 256, MH_SMEM, stream>>>(q, khi, klo, mhi, mlo);

  (void)hipFuncSetAttribute(reinterpret_cast<const void*>(&attn_kernel),
                            hipFuncAttributeMaxDynamicSharedMemorySize, SMEM_BYTES);
  attn_kernel<<<1024, 512, SMEM_BYTES, stream>>>(x, mhi, mlo, vT, soP, out);
}

// Round 3
// 372.185 us; speedup vs baseline: 1.8959x; 1.6482x over previous
//
#include <hip/hip_runtime.h>

typedef unsigned short u16;
typedef __attribute__((ext_vector_type(8))) short short8;
typedef __attribute__((ext_vector_type(4))) float f32x4;

__device__ __forceinline__ float bf2f(u16 u){ return __uint_as_float(((unsigned)u)<<16); }
__device__ __forceinline__ u16 f2bf(float f){
  unsigned u = __float_as_uint(f);
  unsigned r = u + 0x7fffu + ((u>>16)&1u);   // RNE (no NaN/inf in this problem)
  return (u16)(r>>16);
}

#define MFMA16(a,b,c) __builtin_amdgcn_mfma_f32_16x16x32_bf16(a,b,c,0,0,0)

// ---- attn LDS layout (u16 offsets). Strides 264/72: row-stride ≡ 4 banks →
// fragment reads serialize only to the wave64 minimum (no net conflict).
static constexpr int XS_STR  = 264;
static constexpr int PS_STR  = 72;
static constexpr int WT_STR  = 72;
static constexpr int XHI_OFF = 0;         // 64x264
static constexpr int XLO_OFF = 16896;
static constexpr int GHI_OFF = 33792;     // 64x264 G-hi
static constexpr int GLO_OFF = 50688;     // 64x264 G-lo
static constexpr int XVT_OFF = 33792;     // transient 256x72 Xv^T, aliases Ghi/Glo
static constexpr int PS_OFF  = 67584;     // 64x72
static constexpr int SMF_OFF = 72192;     // 64 rows x 2 halves x (mx,sum) f32
static constexpr int SMEM_BYTES = (72192 + 512)*2;   // 145408 B -> 1 block/CU, 8 waves

// ---- mh LDS
static constexpr int MH_SMEM = 70656*2;   // Qhi/Qlo 64x264 + Chi/Clo 256x72

// ---- ws layout (u16): mhi[524288] | mlo[524288] | khi[65536] | klo[65536]
//                       | vT[65536] | soP[4096 u16 = 2048 f32]   (~2.38 MB)

// prep: 0..63 ksplit | 64..79 vT | 80..335 so | 336..847 zero out
__global__ void prep_kernel(const float* __restrict__ k, const float* __restrict__ v,
                            const float* __restrict__ o, u16* __restrict__ khi,
                            u16* __restrict__ klo, u16* __restrict__ vT,
                            float* __restrict__ soP, float4* __restrict__ outz){
  __shared__ float Ts[64*65];
  const int blk = blockIdx.x, tid = threadIdx.x;
  if (blk < 64){
    int base = blk*1024 + tid*4;
    const float4 f4 = *(const float4*)(k + base);
    ushort4 hv, lv;
    hv.x=f2bf(f4.x); lv.x=f2bf(f4.x-bf2f(hv.x));
    hv.y=f2bf(f4.y); lv.y=f2bf(f4.y-bf2f(hv.y));
    hv.z=f2bf(f4.z); lv.z=f2bf(f4.z-bf2f(hv.z));
    hv.w=f2bf(f4.w); lv.w=f2bf(f4.w-bf2f(hv.w));
    *(ushort4*)&khi[base] = hv;
    *(ushort4*)&klo[base] = lv;
  } else if (blk < 80){
    int t = blk - 64;
    const int bi = (t>>2)<<6, bj = (t&3)<<6;
    #pragma unroll
    for (int p=0;p<4;p++){
      int idx4 = tid + (p<<8);
      int i = idx4 >> 4, c4 = (idx4 & 15) << 2;
      const float4 f4 = *(const float4*)(v + ((bi+i)<<8) + bj + c4);
      Ts[i*65+c4]=f4.x; Ts[i*65+c4+1]=f4.y; Ts[i*65+c4+2]=f4.z; Ts[i*65+c4+3]=f4.w;
    }
    __syncthreads();
    #pragma unroll
    for (int p=0;p<2;p++){
      int ch = tid + (p<<8);
      int j = ch >> 3, i8 = (ch & 7) << 3;
      short8 t8;
      #pragma unroll
      for (int e=0;e<8;e++) t8[e] = (short)f2bf(Ts[(i8+e)*65 + j]);
      *(short8*)&vT[((bj+j)<<8) + bi + i8] = t8;
    }
  } else if (blk < 336){
    int p = blk - 80;                      // 256 blocks: 8 h x 32 chunks of 8 rows
    int h = p >> 5, base = (p & 31) << 3;
    int w = tid >> 6, l = tid & 63;
    #pragma unroll
    for (int i=0;i<2;i++){
      int row = base + w*2 + i;
      const float4 f4 = *(const float4*)(o + (((h<<8)+row)<<8) + (l<<2));
      float s = f4.x + f4.y + f4.z + f4.w;
      #pragma unroll
      for (int off=32; off>=1; off>>=1) s += __shfl_xor(s, off, 64);
      if (l==0) soP[(h<<8)+row] = s;
    }
  } else {
    int z = blk - 336;                     // 512 blocks x 4096 float4
    const float4 zf4 = {0.f,0.f,0.f,0.f};
    #pragma unroll
    for (int i=0;i<16;i++) outz[z*4096 + i*256 + tid] = zf4;
  }
}

// MhT[h][dp][d] = sum_ko q[h][d][ko]*k[dp][ko], hi/lo bf16 via 3-term MFMA
__global__ __launch_bounds__(256,1) void mh_kernel(
    const float* __restrict__ q, const u16* __restrict__ khi,
    const u16* __restrict__ klo, u16* __restrict__ mhi, u16* __restrict__ mlo)
{
  extern __shared__ u16 sm[];
  u16* Qhi = sm;
  u16* Qlo = sm + 16896;
  u16* Chi = sm + 33792;
  u16* Clo = sm + 52224;

  const int tid = threadIdx.x;
  const int w = tid >> 6, lane = tid & 63;
  const int quad = lane >> 4, m16 = lane & 15;
  const int cw = w << 6, koq = quad << 3;
  const int h = blockIdx.x >> 2, dt = (blockIdx.x & 3) << 6;

  #pragma unroll
  for (int i=0;i<16;i++){
    int idx4 = i*256 + tid;
    int tr = idx4 >> 6, c4 = (idx4 & 63) << 2;
    const float4 xv = *(const float4*)(q + (((h<<8)+dt+tr)<<8) + c4);
    ushort4 hv, lv;
    hv.x=f2bf(xv.x); lv.x=f2bf(xv.x-bf2f(hv.x));
    hv.y=f2bf(xv.y); lv.y=f2bf(xv.y-bf2f(hv.y));
    hv.z=f2bf(xv.z); lv.z=f2bf(xv.z-bf2f(hv.z));
    hv.w=f2bf(xv.w); lv.w=f2bf(xv.w-bf2f(hv.w));
    *(ushort4*)&Qhi[tr*XS_STR + c4] = hv;
    *(ushort4*)&Qlo[tr*XS_STR + c4] = lv;
  }
  __syncthreads();

  const f32x4 zf = {0.f,0.f,0.f,0.f};
  f32x4 acc[4][4];
  #pragma unroll
  for (int r=0;r<4;r++)
    #pragma unroll
    for (int c=0;c<4;c++) acc[r][c] = zf;

  short8 Bh[2][4], Bl[2][4];
  #pragma unroll
  for (int c=0;c<4;c++){
    Bh[0][c] = *(const short8*)&khi[(cw + c*16 + m16)*256 + koq];
    Bl[0][c] = *(const short8*)&klo[(cw + c*16 + m16)*256 + koq];
  }
  #pragma unroll
  for (int kk=0;kk<8;kk++){
    const int cur = kk&1, nxt = cur^1;
    if (kk<7){
      const int ko2 = ((kk+1)<<5) + koq;
      #pragma unroll
      for (int c=0;c<4;c++){
        Bh[nxt][c] = *(const short8*)&khi[(cw + c*16 + m16)*256 + ko2];
        Bl[nxt][c] = *(const short8*)&klo[(cw + c*16 + m16)*256 + ko2];
      }
    }
    const int ko = (kk<<5) + koq;
    short8 Ah[4], Al[4];
    #pragma unroll
    for (int r=0;r<4;r++) Ah[r] = *(const short8*)&Qhi[(r*16+m16)*XS_STR + ko];
    #pragma unroll
    for (int r=0;r<4;r++) Al[r] = *(const short8*)&Qlo[(r*16+m16)*XS_STR + ko];
    #pragma unroll
    for (int r=0;r<4;r++)
      #pragma unroll
      for (int c=0;c<4;c++){
        acc[r][c] = MFMA16(Ah[r], Bh[cur][c], acc[r][c]);
        acc[r][c] = MFMA16(Ah[r], Bl[cur][c], acc[r][c]);
        acc[r][c] = MFMA16(Al[r], Bh[cur][c], acc[r][c]);
      }
  }

  #pragma unroll
  for (int r=0;r<4;r++)
    #pragma unroll
    for (int c=0;c<4;c++)
      #pragma unroll
      for (int g=0; g<4; g++){
        int drow = r*16 + quad*4 + g;
        int dp   = cw + c*16 + m16;
        float vv = acc[r][c][g];
        u16 hh = f2bf(vv);
        Chi[dp*WT_STR + drow] = hh;
        Clo[dp*WT_STR + drow] = f2bf(vv - bf2f(hh));
      }
  __syncthreads();

  #pragma unroll
  for (int p=0;p<8;p++){
    int ch = tid + (p<<8);
    int dp = ch >> 3, i8 = (ch & 7) << 3;
    *(int4*)&mhi[(((h<<8)+dp)<<8) + dt + i8] = *(const int4*)&Chi[dp*WT_STR + i8];
    *(int4*)&mlo[(((h<<8)+dp)<<8) + dt + i8] = *(const int4*)&Clo[dp*WT_STR + i8];
  }
}

// Merged attention: blocks [0,512) branch 0 (per-(b,y), heads 0..3),
// [512,1024) branch 1 (per-(b,x), heads 4..7). out pre-zeroed; atomicAdd.
// 8 waves (512 thr): mm3/Xv/Y split 4rt x 2ct (dbuf prefetch); logits 16-row
// x 32-z, ALL operands from LDS (no XB persistence: the 128-VGPR allocator
// cap is hard - round-1/2 showed exceeding it spills to scratch, +255MB
// FETCH). Ghi+Glo written together (dual buffer) -> 3 barriers/head, no Glo
// readback pass. Y B-side (Xv^T) hoisted to 16 VGPRs once; Xv^T LDS region
// is transient and aliases Ghi/Glo. Persistent regs: Z(32)+XvB(16)=48, i.e.
// 48 below round-0's fit-at-128 working point.
// Tripwires: VGPR_Count<=128, FETCH ~47MB, WRITE ~77MB (else spill).
__global__ __launch_bounds__(512,2) void attn_kernel(
    const float* __restrict__ x, const u16* __restrict__ mhiP,
    const u16* __restrict__ mloP, const u16* __restrict__ vT,
    const float* __restrict__ soP, float* __restrict__ out)
{
  extern __shared__ u16 sm[];
  u16* Xhi = sm + XHI_OFF;
  u16* Xlo = sm + XLO_OFF;
  u16* Ghi = sm + GHI_OFF;
  u16* Glo = sm + GLO_OFF;
  u16* Xvt = sm + XVT_OFF;
  u16* Ps  = sm + PS_OFF;
  float* SMf = (float*)(sm + SMF_OFF);   // [row][half][mx,sum]

  const int tid  = threadIdx.x;
  const int w    = tid >> 6, lane = tid & 63;
  const int quad = lane >> 4, m16 = lane & 15;
  const int br   = blockIdx.x >> 9;
  const int idx  = blockIdx.x & 511;
  const int b    = idx >> 6, s = idx & 63;
  const int cw   = w << 5;            // 32-col strip for mm3/Xv/Y
  const int rs   = (w >> 1) << 4;     // logits: 16-row strip
  const int zh   = w & 1;             // logits: z half (32 cols)
  const int koq  = quad << 3;

  auto tok = [&](int t)->int {
    int m = br ? s : t;
    int n = br ? t : s;
    return (((b<<6) + m) << 14) + (n << 8);
  };

  // ---- stage X hi/lo (4096 float4, 8 iters x 512 threads)
  #pragma unroll
  for (int i=0;i<8;i++){
    int idx4 = i*512 + tid;
    int tr = idx4 >> 6, c4 = (idx4 & 63) << 2;
    const float4 xv = *(const float4*)(x + tok(tr) + c4);
    ushort4 hv, lv;
    hv.x=f2bf(xv.x); lv.x=f2bf(xv.x-bf2f(hv.x));
    hv.y=f2bf(xv.y); lv.y=f2bf(xv.y-bf2f(hv.y));
    hv.z=f2bf(xv.z); lv.z=f2bf(xv.z-bf2f(hv.z));
    hv.w=f2bf(xv.w); lv.w=f2bf(xv.w-bf2f(hv.w));
    *(ushort4*)&Xhi[tr*XS_STR + c4] = hv;
    *(ushort4*)&Xlo[tr*XS_STR + c4] = lv;
  }
  __syncthreads();

  const f32x4 zf = {0.f,0.f,0.f,0.f};
  f32x4 acc[4][2];

  // ---- Xv = Xhi @ vT over wave's 32 cols; store Xv^T (unscaled) in LDS
  // (transient: aliases Ghi/Glo; consumed into XvB regs below)
  {
    #pragma unroll
    for (int r=0;r<4;r++){ acc[r][0] = zf; acc[r][1] = zf; }
    #pragma unroll
    for (int kk=0;kk<8;kk++){
      const int ko = (kk<<5) + koq;
      short8 A[4], Bf[2];
      #pragma unroll
      for (int r=0;r<4;r++) A[r]  = *(const short8*)&Xhi[(r*16+m16)*XS_STR + ko];
      #pragma unroll
      for (int c=0;c<2;c++) Bf[c] = *(const short8*)&vT[(cw + c*16 + m16)*256 + ko];
      #pragma unroll
      for (int r=0;r<4;r++)
        #pragma unroll
        for (int c=0;c<2;c++) acc[r][c] = MFMA16(A[r], Bf[c], acc[r][c]);
    }
    #pragma unroll
    for (int r=0;r<4;r++)
      #pragma unroll
      for (int c=0;c<2;c++)
        #pragma unroll
        for (int g=0; g<4; g++){
          int z  = r*16 + quad*4 + g;
          int vc = cw + c*16 + m16;
          Xvt[vc*WT_STR + z] = f2bf(acc[r][c][g]);
        }
  }
  // Each wave reads back only its own cw strip (written by its own lanes) ->
  // no cross-wave visibility needed before the read; one barrier after the
  // reads protects the aliased region from head-0 G writes.
  short8 XvB[2][2];
  #pragma unroll
  for (int kk=0;kk<2;kk++)
    #pragma unroll
    for (int c=0;c<2;c++)
      XvB[kk][c] = *(const short8*)&Xvt[(cw + c*16 + m16)*WT_STR + (kk<<5) + koq];
  __syncthreads();                       // Xvt reads done -> Ghi/Glo may overwrite

  f32x4 Z[4][2];
  #pragma unroll
  for (int r=0;r<4;r++){ Z[r][0] = zf; Z[r][1] = zf; }

  for (int h=0; h<4; h++){
    const int gh = br*4 + h;
    const u16* __restrict__ Whi = mhiP + gh*65536;
    const u16* __restrict__ Wlo = mloP + gh*65536;

    // ---- G = X @ Mh[gh] (3-term hi/lo) over wave's 32-col strip, dbuf B-loads
    #pragma unroll
    for (int r=0;r<4;r++){ acc[r][0] = zf; acc[r][1] = zf; }
    {
      short8 Bh[2][2], Bl[2][2];
      #pragma unroll
      for (int c=0;c<2;c++){
        Bh[0][c] = *(const short8*)&Whi[(cw + c*16 + m16)*256 + koq];
        Bl[0][c] = *(const short8*)&Wlo[(cw + c*16 + m16)*256 + koq];
      }
      #pragma unroll
      for (int kk=0;kk<8;kk++){
        const int cur = kk&1, nxt = cur^1;
        if (kk<7){
          const int ko2 = ((kk+1)<<5) + koq;
          #pragma unroll
          for (int c=0;c<2;c++){
            Bh[nxt][c] = *(const short8*)&Whi[(cw + c*16 + m16)*256 + ko2];
            Bl[nxt][c] = *(const short8*)&Wlo[(cw + c*16 + m16)*256 + ko2];
          }
        }
        const int ko = (kk<<5) + koq;
        short8 Ah[4], Al[4];
        #pragma unroll
        for (int r=0;r<4;r++) Ah[r] = *(const short8*)&Xhi[(r*16+m16)*XS_STR + ko];
        #pragma unroll
        for (int r=0;r<4;r++) Al[r] = *(const short8*)&Xlo[(r*16+m16)*XS_STR + ko];
        #pragma unroll
        for (int r=0;r<4;r++)
          #pragma unroll
          for (int c=0;c<2;c++){
            acc[r][c] = MFMA16(Ah[r], Bh[cur][c], acc[r][c]);
            acc[r][c] = MFMA16(Ah[r], Bl[cur][c], acc[r][c]);
            acc[r][c] = MFMA16(Al[r], Bh[cur][c], acc[r][c]);
          }
      }
    }
    // ---- write Ghi AND Glo together (dual buffer; kills the readback pass)
    #pragma unroll
    for (int r=0;r<4;r++)
      #pragma unroll
      for (int c=0;c<2;c++)
        #pragma unroll
        for (int g=0; g<4; g++){
          int row = r*16 + quad*4 + g;
          int col = cw + c*16 + m16;
          float vv = acc[r][c][g];
          u16 hh = f2bf(vv);
          Ghi[row*XS_STR + col] = hh;
          Glo[row*XS_STR + col] = f2bf(vv - bf2f(hh));
        }
    __syncthreads();                     // bar1: Ghi+Glo visible

    // ---- logits: Ghi@Xhi^T + Ghi@Xlo^T + Glo@Xhi^T, one pass, all from LDS.
    // Rows rs..rs+16, z half zh.
    f32x4 L[2];
    L[0] = zf; L[1] = zf;
    #pragma unroll
    for (int kk=0;kk<8;kk++){
      const int ko = (kk<<5) + koq;
      short8 Ahi = *(const short8*)&Ghi[(rs+m16)*XS_STR + ko];
      short8 Alo = *(const short8*)&Glo[(rs+m16)*XS_STR + ko];
      #pragma unroll
      for (int c=0;c<2;c++){
        short8 Bxh = *(const short8*)&Xhi[((zh<<5) + c*16 + m16)*XS_STR + ko];
        short8 Bxl = *(const short8*)&Xlo[((zh<<5) + c*16 + m16)*XS_STR + ko];
        L[c] = MFMA16(Ahi, Bxh, L[c]);
        L[c] = MFMA16(Ahi, Bxl, L[c]);
        L[c] = MFMA16(Alo, Bxh, L[c]);
      }
    }

    // ---- softmax: local (32-z half) max/sum, cross-wave merge via SMf
    float mxl[4], sml[4];
    #pragma unroll
    for (int g=0; g<4; g++){
      float mx = fmaxf(L[0][g], L[1][g]);
      #pragma unroll
      for (int off=1; off<16; off<<=1) mx = fmaxf(mx, __shfl_xor(mx, off, 64));
      float sum = 0.f;
      #pragma unroll
      for (int c=0;c<2;c++){ float e = __expf(L[c][g]-mx); L[c][g] = e; sum += e; }
      #pragma unroll
      for (int off=1; off<16; off<<=1) sum += __shfl_xor(sum, off, 64);
      mxl[g] = mx; sml[g] = sum;
      if (m16 == 0){
        int row = rs + quad*4 + g;
        SMf[row*4 + zh*2]     = mx;
        SMf[row*4 + zh*2 + 1] = sum;
      }
    }
    __syncthreads();                     // bar2: SMf visible (G reads also done)
    #pragma unroll
    for (int g=0; g<4; g++){
      int row = rs + quad*4 + g;
      float mxo = SMf[row*4 + (zh^1)*2];
      float smo = SMf[row*4 + (zh^1)*2 + 1];
      float M   = fmaxf(mxl[g], mxo);
      float al  = __expf(mxl[g]-M), ao = __expf(mxo-M);
      float scale = al / (sml[g]*al + smo*ao);
      #pragma unroll
      for (int c=0;c<2;c++)
        Ps[row*PS_STR + (zh<<5) + c*16 + m16] = f2bf(L[c][g]*scale);
    }
    __syncthreads();                     // bar3: Ps visible

    // ---- Y = P @ Xv over wave's 32 cols (B from regs); Z += so * Y
    #pragma unroll
    for (int r=0;r<4;r++){ acc[r][0] = zf; acc[r][1] = zf; }
    #pragma unroll
    for (int kk=0;kk<2;kk++){
      const int ko = (kk<<5) + koq;
      short8 Ap[4];
      #pragma unroll
      for (int r=0;r<4;r++) Ap[r] = *(const short8*)&Ps[(r*16+m16)*PS_STR + ko];
      #pragma unroll
      for (int r=0;r<4;r++)
        #pragma unroll
        for (int c=0;c<2;c++) acc[r][c] = MFMA16(Ap[r], XvB[kk][c], acc[r][c]);
    }
    float sc[2];
    sc[0] = soP[gh*256 + cw + m16];
    sc[1] = soP[gh*256 + cw + 16 + m16];
    #pragma unroll
    for (int r=0;r<4;r++)
      #pragma unroll
      for (int c=0;c<2;c++)
        #pragma unroll
        for (int g=0; g<4; g++) Z[r][c][g] += sc[c]*acc[r][c][g];
    // loop boundary safe with 3 barriers/head: head h+1's G/SMf/Ps writes are
    // barrier-ordered (via bar1/bar2 of h+1) after every wave's reads of the
    // same regions for head h (reads precede bar2(h)/bar3(h) respectively).
  }

  // ---- epilogue: atomic accumulate into pre-zeroed out
  #pragma unroll
  for (int r=0;r<4;r++)
    #pragma unroll
    for (int c=0;c<2;c++)
      #pragma unroll
      for (int g=0; g<4; g++){
        int t   = r*16 + quad*4 + g;
        int col = cw + c*16 + m16;
        atomicAdd(&out[tok(t) + col], Z[r][c][g]);
      }
}

extern "C" void kernel_launch(void* const* d_in, const int* in_sizes, int n_in,
                              void* d_out, int out_size, void* d_ws, size_t ws_size,
                              hipStream_t stream) {
  const float* x = (const float*)d_in[0];
  const float* q = (const float*)d_in[1];
  const float* k = (const float*)d_in[2];
  const float* v = (const float*)d_in[3];
  const float* o = (const float*)d_in[4];
  u16* ws   = (u16*)d_ws;                    // ~2.38 MB
  u16* mhi  = ws;
  u16* mlo  = ws + 524288;
  u16* khi  = ws + 1048576;
  u16* klo  = ws + 1114112;
  u16* vT   = ws + 1179648;
  float* soP = (float*)(ws + 1245184);
  float* out = (float*)d_out;

  prep_kernel<<<848, 256, 0, stream>>>(k, v, o, khi, klo, vT, soP, (float4*)d_out);
  (void)hipFuncSetAttribute(reinterpret_cast<const void*>(&mh_kernel),
                            hipFuncAttributeMaxDynamicSharedMemorySize, MH_SMEM);
  mh_kernel<<<32, 256, MH_SMEM, stream>>>(q, khi, klo, mhi, mlo);

  (void)hipFuncSetAttribute(reinterpret_cast<const void*>(&attn_kernel),
                            hipFuncAttributeMaxDynamicSharedMemorySize, SMEM_BYTES);
  attn_kernel<<<1024, 512, SMEM_BYTES, stream>>>(x, mhi, mlo, vT, soP, out);
}